// Round 1
// baseline (1821.107 us; speedup 1.0000x reference)
//
#include <hip/hip_runtime.h>
#include <hip/hip_bf16.h>
#include <math.h>

#define HH 56
#define WW 56
#define HWv 3136
#define NROWS 25088          // B*H*W
#define DIMK 1792
#define CIN 1794
#define COUT 1792
#define MM 3136
#define MPAD 3200

typedef __bf16 bf16_t;
typedef __bf16 bf16x8 __attribute__((ext_vector_type(8)));
typedef float f32x4 __attribute__((ext_vector_type(4)));

// ---------------- prep kernels ----------------

__global__ __launch_bounds__(256) void k_convw(const float* __restrict__ cw, bf16_t* __restrict__ wb) {
    int idx = blockIdx.x * 256 + threadIdx.x;
    if (idx >= COUT * DIMK) return;
    int o = idx / DIMK, c = idx - o * DIMK;
    wb[idx] = (bf16_t)cw[(size_t)o * CIN + c];
}

__global__ __launch_bounds__(256) void k_bankT(const float* __restrict__ bank, bf16_t* __restrict__ bt) {
    int idx = blockIdx.x * 256 + threadIdx.x;      // over MPAD*DIMK
    int m = idx / DIMK, c = idx - m * DIMK;
    float v = (m < MM) ? bank[(size_t)c * MM + m] : 0.f;
    bt[idx] = (bf16_t)v;
}

__global__ __launch_bounds__(256) void k_csq(const bf16_t* __restrict__ bt, float* __restrict__ csq) {
    int m = blockIdx.x;
    int tid = threadIdx.x;
    float s = 0.f;
    for (int c = tid; c < DIMK; c += 256) { float v = (float)bt[(size_t)m * DIMK + c]; s += v * v; }
    __shared__ float red[256];
    red[tid] = s; __syncthreads();
    for (int off = 128; off > 0; off >>= 1) { if (tid < off) red[tid] += red[tid + off]; __syncthreads(); }
    if (tid == 0) csq[m] = red[0];
}

__global__ __launch_bounds__(256) void k_pool1(const float* __restrict__ f1, bf16_t* __restrict__ inp) {
    int c = threadIdx.x;           // 0..255
    int hw = blockIdx.x;           // 0..3135
    int b = blockIdx.y;
    int h = hw / WW, w = hw - h * WW;
    const float* base = f1 + (size_t)(b * 256 + c) * HWv;
    float s = 0.f;
    #pragma unroll
    for (int dy = -1; dy <= 1; ++dy) {
        int y = h + dy; if ((unsigned)y >= HH) continue;
        #pragma unroll
        for (int dx = -1; dx <= 1; ++dx) {
            int x = w + dx; if ((unsigned)x >= WW) continue;
            s += base[y * WW + x];
        }
    }
    inp[(size_t)(b * HWv + hw) * DIMK + c] = (bf16_t)(s * (1.f / 9.f));
}

__global__ __launch_bounds__(256) void k_pool_s(const float* __restrict__ in, float* __restrict__ out,
                                                int S, int total) {
    int idx = blockIdx.x * 256 + threadIdx.x;
    if (idx >= total) return;
    int x = idx % S; int y = (idx / S) % S; int bc = idx / (S * S);
    const float* base = in + (size_t)bc * S * S;
    float s = 0.f;
    for (int dy = -1; dy <= 1; ++dy) {
        int yy = y + dy; if ((unsigned)yy >= (unsigned)S) continue;
        for (int dx = -1; dx <= 1; ++dx) {
            int xx = x + dx; if ((unsigned)xx >= (unsigned)S) continue;
            s += base[yy * S + xx];
        }
    }
    out[idx] = s * (1.f / 9.f);
}

__global__ __launch_bounds__(256) void k_resize(const float* __restrict__ p, bf16_t* __restrict__ inp,
                                                int S, int C, int coff, float scale, float shift) {
    int c = blockIdx.z * 256 + threadIdx.x;
    int hw = blockIdx.x, b = blockIdx.y;
    int h = hw / WW, w = hw - h * WW;
    float sy = scale * h + shift;
    float sx = scale * w + shift;
    float y0f = floorf(sy), x0f = floorf(sx);
    int y0 = (int)y0f, x0 = (int)x0f;
    float fy = sy - y0f, fx = sx - x0f;
    int iy0 = y0 < 0 ? 0 : (y0 > S - 1 ? S - 1 : y0);
    int iy1 = (y0 + 1) < 0 ? 0 : ((y0 + 1) > S - 1 ? S - 1 : y0 + 1);
    int ix0 = x0 < 0 ? 0 : (x0 > S - 1 ? S - 1 : x0);
    int ix1 = (x0 + 1) < 0 ? 0 : ((x0 + 1) > S - 1 ? S - 1 : x0 + 1);
    const float* base = p + (size_t)(b * C + c) * S * S;
    float v00 = base[iy0 * S + ix0], v01 = base[iy0 * S + ix1];
    float v10 = base[iy1 * S + ix0], v11 = base[iy1 * S + ix1];
    float v = (1.f - fy) * ((1.f - fx) * v00 + fx * v01) + fy * ((1.f - fx) * v10 + fx * v11);
    inp[(size_t)(b * HWv + hw) * DIMK + coff + c] = (bf16_t)v;
}

// ---------------- GEMM core (m97-style 128x128 tile, BK=64) ----------------

__device__ __forceinline__ void gemm_core(const bf16_t* __restrict__ A, const bf16_t* __restrict__ Bm,
                                          int n0, int j0, f32x4 acc[4][4],
                                          bf16_t* sA, bf16_t* sB) {
    const int tid = threadIdx.x;
    const int lane = tid & 63;
    const int wv = tid >> 6;
    const int wr = wv >> 1, wc = wv & 1;
    const int lr = lane & 15, lg = lane >> 4;

    #pragma unroll
    for (int i = 0; i < 4; ++i)
        #pragma unroll
        for (int j = 0; j < 4; ++j) acc[i][j] = (f32x4){0.f, 0.f, 0.f, 0.f};

    for (int k0 = 0; k0 < DIMK; k0 += 64) {
        __syncthreads();   // protect LDS from overwrite
        #pragma unroll
        for (int r = 0; r < 4; ++r) {
            int q = r * 256 + tid;
            int row = q >> 3, col = (q & 7) * 8;
            __builtin_amdgcn_global_load_lds(
                (__attribute__((address_space(1))) void*)(A + (size_t)(n0 + row) * DIMK + k0 + col),
                (__attribute__((address_space(3))) void*)(sA + q * 8), 16, 0, 0);
        }
        #pragma unroll
        for (int r = 0; r < 4; ++r) {
            int q = r * 256 + tid;
            int row = q >> 3, col = (q & 7) * 8;
            __builtin_amdgcn_global_load_lds(
                (__attribute__((address_space(1))) void*)(Bm + (size_t)(j0 + row) * DIMK + k0 + col),
                (__attribute__((address_space(3))) void*)(sB + q * 8), 16, 0, 0);
        }
        __syncthreads();   // drains vmcnt(0): tiles resident
        #pragma unroll
        for (int kk = 0; kk < 2; ++kk) {
            bf16x8 aF[4], bF[4];
            #pragma unroll
            for (int fm = 0; fm < 4; ++fm)
                aF[fm] = *(const bf16x8*)(sA + (wr * 64 + fm * 16 + lr) * 64 + kk * 32 + lg * 8);
            #pragma unroll
            for (int fn = 0; fn < 4; ++fn)
                bF[fn] = *(const bf16x8*)(sB + (wc * 64 + fn * 16 + lr) * 64 + kk * 32 + lg * 8);
            #pragma unroll
            for (int fm = 0; fm < 4; ++fm)
                #pragma unroll
                for (int fn = 0; fn < 4; ++fn)
                    acc[fm][fn] = __builtin_amdgcn_mfma_f32_16x16x32_bf16(aF[fm], bF[fn], acc[fm][fn], 0, 0, 0);
        }
    }
}

// GEMM1: feats[n,o] = bf16( inp[n,:]·wb[o,:] + cb[o] + xx*cw[o,1792] + yy*cw[o,1793] )
__global__ __launch_bounds__(256) void k_gemm1(const bf16_t* __restrict__ inp, const bf16_t* __restrict__ wb,
                                               const float* __restrict__ cw, const float* __restrict__ cb,
                                               bf16_t* __restrict__ feats) {
    __shared__ __align__(16) bf16_t sA[128 * 64];
    __shared__ __align__(16) bf16_t sB[128 * 64];
    int n0 = blockIdx.y * 128, j0 = blockIdx.x * 128;
    f32x4 acc[4][4];
    gemm_core(inp, wb, n0, j0, acc, sA, sB);
    const int lane = threadIdx.x & 63, wv = threadIdx.x >> 6;
    const int wr = wv >> 1, wc = wv & 1, lr = lane & 15, lg = lane >> 4;
    #pragma unroll
    for (int fm = 0; fm < 4; ++fm) {
        #pragma unroll
        for (int v = 0; v < 4; ++v) {
            int n = n0 + wr * 64 + fm * 16 + lg * 4 + v;
            int hw = n % HWv;
            int h = hw / WW, w = hw - h * WW;
            float xx = (2.f / 55.f) * w - 1.f;
            float yy = (2.f / 55.f) * h - 1.f;
            #pragma unroll
            for (int fn = 0; fn < 4; ++fn) {
                int o = j0 + wc * 64 + fn * 16 + lr;
                float phi = acc[fm][fn][v] + cb[o] + xx * cw[(size_t)o * CIN + DIMK] + yy * cw[(size_t)o * CIN + DIMK + 1];
                feats[(size_t)n * DIMK + o] = (bf16_t)phi;
            }
        }
    }
}

// GEMM2: dist[n-nbase, m] = sqrt(fsq[n] + csq[m] - 2*feats[n,:]·bt[m,:])
__global__ __launch_bounds__(256) void k_gemm2(const bf16_t* __restrict__ feats, const bf16_t* __restrict__ bt,
                                               const float* __restrict__ fsq, const float* __restrict__ csq,
                                               float* __restrict__ dist, int nbase) {
    __shared__ __align__(16) bf16_t sA[128 * 64];
    __shared__ __align__(16) bf16_t sB[128 * 64];
    int n0 = nbase + blockIdx.y * 128, j0 = blockIdx.x * 128;
    f32x4 acc[4][4];
    gemm_core(feats, bt, n0, j0, acc, sA, sB);
    const int lane = threadIdx.x & 63, wv = threadIdx.x >> 6;
    const int wr = wv >> 1, wc = wv & 1, lr = lane & 15, lg = lane >> 4;
    #pragma unroll
    for (int fm = 0; fm < 4; ++fm) {
        #pragma unroll
        for (int v = 0; v < 4; ++v) {
            int n = n0 + wr * 64 + fm * 16 + lg * 4 + v;
            float fs = fsq[n];
            #pragma unroll
            for (int fn = 0; fn < 4; ++fn) {
                int m = j0 + wc * 64 + fn * 16 + lr;
                if (m < MM) {
                    float d2 = fs + csq[m] - 2.f * acc[fm][fn][v];
                    dist[(size_t)(n - nbase) * MM + m] = sqrtf(fmaxf(d2, 0.f));
                }
            }
        }
    }
}

__global__ __launch_bounds__(256) void k_fsq(const bf16_t* __restrict__ feats, float* __restrict__ fsq) {
    int n = blockIdx.x * 4 + (threadIdx.x >> 6);
    int lane = threadIdx.x & 63;
    const bf16_t* row = feats + (size_t)n * DIMK;
    float s = 0.f;
    #pragma unroll
    for (int t = 0; t < 28; ++t) { float v = (float)row[t * 64 + lane]; s += v * v; }
    #pragma unroll
    for (int off = 32; off; off >>= 1) s += __shfl_xor(s, off, 64);
    if (lane == 0) fsq[n] = s;
}

__global__ __launch_bounds__(256) void k_topk(const float* __restrict__ dist, float* __restrict__ out, int nbase) {
    int r = blockIdx.x * 4 + (threadIdx.x >> 6);   // row within chunk
    int lane = threadIdx.x & 63;
    const float* row = dist + (size_t)r * MM;
    const float INF = __builtin_inff();
    float d0 = INF, d1 = INF, d2 = INF;
    for (int t = 0; t < 49; ++t) {
        float v = row[t * 64 + lane];
        if (v < d2) {
            if (v < d1) {
                d2 = d1;
                if (v < d0) { d1 = d0; d0 = v; } else d1 = v;
            } else d2 = v;
        }
    }
    #pragma unroll
    for (int off = 1; off < 64; off <<= 1) {
        float e0 = __shfl_xor(d0, off, 64);
        float e1 = __shfl_xor(d1, off, 64);
        float e2 = __shfl_xor(d2, off, 64);
        // merge two sorted triples -> smallest three
        bool t0 = d0 <= e0;
        float c0 = t0 ? d0 : e0;
        float x0 = t0 ? d1 : d0, x1 = t0 ? d2 : d1;   // advanced a-list heads
        float y0 = t0 ? e0 : e1, y1 = t0 ? e1 : e2;   // advanced b-list heads
        bool t1 = x0 <= y0;
        float c1 = t1 ? x0 : y0;
        float c2 = t1 ? fminf(x1, y0) : fminf(x0, y1);
        d0 = c0; d1 = c1; d2 = c2;
    }
    if (lane == 0) {
        float e1 = expf(d0 - d1), e2 = expf(d0 - d2);
        float w0 = 1.f / (1.f + e1 + e2);
        out[nbase + r] = w0 * d0;
    }
}

// ---------------- launch ----------------

extern "C" void kernel_launch(void* const* d_in, const int* in_sizes, int n_in,
                              void* d_out, int out_size, void* d_ws, size_t ws_size,
                              hipStream_t stream) {
    const float* f1   = (const float*)d_in[0];
    const float* f2   = (const float*)d_in[1];
    const float* f3   = (const float*)d_in[2];
    const float* cw   = (const float*)d_in[3];
    const float* cb   = (const float*)d_in[4];
    const float* bank = (const float*)d_in[5];
    float* out = (float*)d_out;
    char* ws = (char*)d_ws;

    size_t off = 0;
    auto alloc = [&](size_t bytes) { size_t o = off; off = (off + bytes + 255) & ~(size_t)255; return o; };
    bf16_t* wb    = (bf16_t*)(ws + alloc((size_t)COUT * DIMK * 2));
    bf16_t* bt    = (bf16_t*)(ws + alloc((size_t)MPAD * DIMK * 2));
    float*  fsq   = (float*)(ws + alloc((size_t)NROWS * 4));
    float*  csq   = (float*)(ws + alloc((size_t)MPAD * 4));
    float*  p2    = (float*)(ws + alloc((size_t)8 * 512 * 28 * 28 * 4));
    float*  p3    = (float*)(ws + alloc((size_t)8 * 1024 * 14 * 14 * 4));
    bf16_t* inp   = (bf16_t*)(ws + alloc((size_t)NROWS * DIMK * 2));
    bf16_t* feats = (bf16_t*)(ws + alloc((size_t)NROWS * DIMK * 2));
    size_t distoff = off;
    float* dist = (float*)(ws + distoff);
    size_t avail = ws_size > distoff ? ws_size - distoff : 0;
    long maxrows = (long)(avail / ((size_t)MM * 4));
    int chunk = (int)((maxrows / 128) * 128);
    if (chunk > NROWS) chunk = NROWS;
    if (chunk < 128) chunk = 128;

    k_convw<<<dim3((COUT * DIMK + 255) / 256), dim3(256), 0, stream>>>(cw, wb);
    k_bankT<<<dim3((MPAD * DIMK) / 256), dim3(256), 0, stream>>>(bank, bt);
    k_csq<<<dim3(MPAD), dim3(256), 0, stream>>>(bt, csq);
    k_pool1<<<dim3(HWv, 8), dim3(256), 0, stream>>>(f1, inp);
    k_pool_s<<<dim3((8 * 512 * 784 + 255) / 256), dim3(256), 0, stream>>>(f2, p2, 28, 8 * 512 * 784);
    k_pool_s<<<dim3((8 * 1024 * 196 + 255) / 256), dim3(256), 0, stream>>>(f3, p3, 14, 8 * 1024 * 196);
    k_resize<<<dim3(HWv, 8, 2), dim3(256), 0, stream>>>(p2, inp, 28, 512, 256, 0.5f, -0.25f);
    k_resize<<<dim3(HWv, 8, 4), dim3(256), 0, stream>>>(p3, inp, 14, 1024, 768, 0.25f, -0.375f);
    k_gemm1<<<dim3(COUT / 128, NROWS / 128), dim3(256), 0, stream>>>(inp, wb, cw, cb, feats);
    k_fsq<<<dim3(NROWS / 4), dim3(256), 0, stream>>>(feats, fsq);
    for (int n0 = 0; n0 < NROWS; n0 += chunk) {
        int rows = (NROWS - n0) < chunk ? (NROWS - n0) : chunk;
        k_gemm2<<<dim3(MPAD / 128, rows / 128), dim3(256), 0, stream>>>(feats, bt, fsq, csq, dist, n0);
        k_topk<<<dim3(rows / 4), dim3(256), 0, stream>>>(dist, out, n0);
    }
}

// Round 2
// 1068.960 us; speedup vs baseline: 1.7036x; 1.7036x over previous
//
#include <hip/hip_runtime.h>
#include <hip/hip_bf16.h>
#include <math.h>

#define HH 56
#define WW 56
#define HWv 3136
#define NROWS 25088          // B*H*W
#define DIMK 1792
#define KP   1920            // padded K stride (30 tiles of 64; tiles 28,29 staged-only)
#define CIN 1794
#define COUT 1792
#define MM 3136
#define MROWS 3328           // 13 * 256
#define JT2 13
#define JT1 7
#define NT 98

typedef __bf16 bf16_t;
typedef __bf16 bf16x8 __attribute__((ext_vector_type(8)));
typedef float f32x4 __attribute__((ext_vector_type(4)));

__device__ __forceinline__ void merge3(float& d0, float& d1, float& d2,
                                       float e0, float e1, float e2) {
    bool t0 = d0 <= e0;
    float c0 = t0 ? d0 : e0;
    float x0 = t0 ? d1 : d0, x1 = t0 ? d2 : d1;
    float y0 = t0 ? e0 : e1, y1 = t0 ? e1 : e2;
    bool t1 = x0 <= y0;
    float c1 = t1 ? x0 : y0;
    float c2 = t1 ? fminf(x1, y0) : fminf(x0, y1);
    d0 = c0; d1 = c1; d2 = c2;
}

__device__ __forceinline__ int xcd_swz(int wg, int nwg) {
    int x = wg & 7, idx = wg >> 3;
    int q = nwg >> 3, r = nwg & 7;
    return (x < r ? x * (q + 1) : r * (q + 1) + (x - r) * q) + idx;
}

__device__ __forceinline__ void block_bar() {
    asm volatile("" ::: "memory");
    __builtin_amdgcn_s_barrier();
    asm volatile("" ::: "memory");
}

// ---------------- prep kernels ----------------

__global__ __launch_bounds__(256) void k_convw(const float* __restrict__ cw, bf16_t* __restrict__ wb) {
    int idx = blockIdx.x * 256 + threadIdx.x;
    if (idx >= COUT * DIMK) return;
    int o = idx / DIMK, c = idx - o * DIMK;
    wb[(size_t)o * KP + c] = (bf16_t)cw[(size_t)o * CIN + c];
}

// tiled transpose bank[C,M] -> bt[MROWS,KP] (bf16), zero pad rows
__global__ __launch_bounds__(256) void k_bankT(const float* __restrict__ bank, bf16_t* __restrict__ bt) {
    __shared__ float tile[64][65];
    int mt = blockIdx.x * 64;   // over MROWS
    int ct = blockIdx.y * 64;   // over DIMK
    int l = threadIdx.x & 63;
    int q = threadIdx.x >> 6;
    if (mt < MM) {
        #pragma unroll
        for (int r = 0; r < 16; ++r) {
            int cl = q * 16 + r;
            tile[cl][l] = bank[(size_t)(ct + cl) * MM + mt + l];
        }
        __syncthreads();
        #pragma unroll
        for (int r = 0; r < 16; ++r) {
            int ml = q * 16 + r;
            bt[(size_t)(mt + ml) * KP + ct + l] = (bf16_t)tile[l][ml];
        }
    } else {
        #pragma unroll
        for (int r = 0; r < 16; ++r) {
            int ml = q * 16 + r;
            bt[(size_t)(mt + ml) * KP + ct + l] = (bf16_t)0.f;
        }
    }
}

__global__ __launch_bounds__(256) void k_csq(const bf16_t* __restrict__ bt, float* __restrict__ csq) {
    int m = blockIdx.x;
    int tid = threadIdx.x;
    float s = 0.f;
    #pragma unroll
    for (int it = 0; it < 7; ++it) {
        float v = (float)bt[(size_t)m * KP + it * 256 + tid];
        s += v * v;
    }
    __shared__ float red[256];
    red[tid] = s; __syncthreads();
    for (int off = 128; off > 0; off >>= 1) { if (tid < off) red[tid] += red[tid + off]; __syncthreads(); }
    if (tid == 0) csq[m] = red[0];
}

__global__ __launch_bounds__(256) void k_pool1(const float* __restrict__ f1, bf16_t* __restrict__ inp) {
    int c = threadIdx.x;
    int hw = blockIdx.x;
    int b = blockIdx.y;
    int h = hw / WW, w = hw - h * WW;
    const float* base = f1 + (size_t)(b * 256 + c) * HWv;
    float s = 0.f;
    #pragma unroll
    for (int dy = -1; dy <= 1; ++dy) {
        int y = h + dy; if ((unsigned)y >= HH) continue;
        #pragma unroll
        for (int dx = -1; dx <= 1; ++dx) {
            int x = w + dx; if ((unsigned)x >= WW) continue;
            s += base[y * WW + x];
        }
    }
    inp[(size_t)(b * HWv + hw) * KP + c] = (bf16_t)(s * (1.f / 9.f));
}

__global__ __launch_bounds__(256) void k_pool_s(const float* __restrict__ in, float* __restrict__ out,
                                                int S, int total) {
    int idx = blockIdx.x * 256 + threadIdx.x;
    if (idx >= total) return;
    int x = idx % S; int y = (idx / S) % S; int bc = idx / (S * S);
    const float* base = in + (size_t)bc * S * S;
    float s = 0.f;
    for (int dy = -1; dy <= 1; ++dy) {
        int yy = y + dy; if ((unsigned)yy >= (unsigned)S) continue;
        for (int dx = -1; dx <= 1; ++dx) {
            int xx = x + dx; if ((unsigned)xx >= (unsigned)S) continue;
            s += base[yy * S + xx];
        }
    }
    out[idx] = s * (1.f / 9.f);
}

__global__ __launch_bounds__(256) void k_resize(const float* __restrict__ p, bf16_t* __restrict__ inp,
                                                int S, int C, int coff, float scale, float shift) {
    int c = blockIdx.z * 256 + threadIdx.x;
    int hw = blockIdx.x, b = blockIdx.y;
    int h = hw / WW, w = hw - h * WW;
    float sy = scale * h + shift;
    float sx = scale * w + shift;
    float y0f = floorf(sy), x0f = floorf(sx);
    int y0 = (int)y0f, x0 = (int)x0f;
    float fy = sy - y0f, fx = sx - x0f;
    int iy0 = y0 < 0 ? 0 : (y0 > S - 1 ? S - 1 : y0);
    int iy1 = (y0 + 1) < 0 ? 0 : ((y0 + 1) > S - 1 ? S - 1 : y0 + 1);
    int ix0 = x0 < 0 ? 0 : (x0 > S - 1 ? S - 1 : x0);
    int ix1 = (x0 + 1) < 0 ? 0 : ((x0 + 1) > S - 1 ? S - 1 : x0 + 1);
    const float* base = p + (size_t)(b * C + c) * S * S;
    float v00 = base[iy0 * S + ix0], v01 = base[iy0 * S + ix1];
    float v10 = base[iy1 * S + ix0], v11 = base[iy1 * S + ix1];
    float v = (1.f - fy) * ((1.f - fx) * v00 + fx * v01) + fy * ((1.f - fx) * v10 + fx * v11);
    inp[(size_t)(b * HWv + hw) * KP + coff + c] = (bf16_t)v;
}

// ---------------- 256x256 8-phase GEMM core ----------------
// lds layout: sA = lds[0..32768), sB = lds[32768..65536)  (bf16 elems)
// each operand: [2 bufs][2 strips/halves][128 rows][64 k]
// A strips: strip s holds global tile-rows { r : (r>>6)&1 == s }, strip-local
// row = (r&63) + 64*(r>>7).  B halves: nh = rows [nh*128, nh*128+128).
// Swizzle (both sides): 16B-granule index g stores source col-granule
// (g&7) ^ ((g>>3)&7); reads XOR the same.

__device__ __forceinline__ void gemm256(const bf16_t* __restrict__ A, const bf16_t* __restrict__ Bm,
                                        int n0, int j0, f32x4 (&acc)[8][4], bf16_t* lds) {
    const int tid = threadIdx.x;
    const int lane = tid & 63;
    const int wid = tid >> 6;
    const int wr = wid >> 2;          // 0..1  (row half of wave)
    const int wc = wid & 3;           // 0..3  (col quarter)
    const int lr = lane & 15;
    const int lg = lane >> 4;

    bf16_t* sA = lds;
    bf16_t* sB = lds + 32768;

    #pragma unroll
    for (int i = 0; i < 8; ++i)
        #pragma unroll
        for (int j = 0; j < 4; ++j) acc[i][j] = (f32x4){0.f, 0.f, 0.f, 0.f};

    const int kg0 = ((lg) ^ (lr & 7)) * 8;
    const int kg1 = ((4 + lg) ^ (lr & 7)) * 8;
    const int brow = (wc * 64 + lr) * 64;
    const int arow = (wr * 64 + lr) * 64;

    // stage one A strip-half (128 strip-rows x 64 k) into dst region
    auto stageA = [&](bf16_t* dst, int s, int kt) {
        #pragma unroll
        for (int r = 0; r < 2; ++r) {
            int g = r * 512 + tid;
            int rp = g >> 3;
            int cb = (g & 7) ^ (rp & 7);
            int rg = (rp & 63) + ((rp >> 6) << 7) + s * 64;
            __builtin_amdgcn_global_load_lds(
                (__attribute__((address_space(1))) void*)(A + (size_t)(n0 + rg) * KP + kt * 64 + cb * 8),
                (__attribute__((address_space(3))) void*)(dst + g * 8), 16, 0, 0);
        }
    };
    // stage one B n-half (128 rows x 64 k)
    auto stageB = [&](bf16_t* dst, int nh, int kt) {
        #pragma unroll
        for (int r = 0; r < 2; ++r) {
            int g = r * 512 + tid;
            int rp = g >> 3;
            int cb = (g & 7) ^ (rp & 7);
            __builtin_amdgcn_global_load_lds(
                (__attribute__((address_space(1))) void*)(Bm + (size_t)(j0 + nh * 128 + rp) * KP + kt * 64 + cb * 8),
                (__attribute__((address_space(3))) void*)(dst + g * 8), 16, 0, 0);
        }
    };

#define PHASE(BUFO, MH, KH, STAGE_CODE, TAIL_CODE)                                         \
    {                                                                                      \
        bf16x8 aF[4], bF[4];                                                               \
        _Pragma("unroll")                                                                  \
        for (int q = 0; q < 4; ++q) {                                                      \
            aF[q] = *(const bf16x8*)(sA + (BUFO) + (MH) * 8192 + q * 1024 + arow + ((KH) ? kg1 : kg0)); \
            bF[q] = *(const bf16x8*)(sB + (BUFO) + q * 1024 + brow + ((KH) ? kg1 : kg0));  \
        }                                                                                  \
        STAGE_CODE;                                                                        \
        block_bar();                                                                       \
        __builtin_amdgcn_s_setprio(1);                                                     \
        _Pragma("unroll")                                                                  \
        for (int q = 0; q < 4; ++q)                                                        \
            _Pragma("unroll")                                                              \
            for (int fn = 0; fn < 4; ++fn)                                                 \
                acc[(MH) * 4 + q][fn] = __builtin_amdgcn_mfma_f32_16x16x32_bf16(           \
                    aF[q], bF[fn], acc[(MH) * 4 + q][fn], 0, 0, 0);                        \
        __builtin_amdgcn_s_setprio(0);                                                     \
        TAIL_CODE;                                                                         \
        block_bar();                                                                       \
    }

    // prologue: tile0 full into buf0, tile1 strip0 into buf1
    stageA(sA + 0,     0, 0);
    stageA(sA + 8192,  1, 0);
    stageB(sB + 0,     0, 0);
    stageB(sB + 8192,  1, 0);
    stageA(sA + 16384, 0, 1);
    asm volatile("s_waitcnt vmcnt(2)" ::: "memory");
    block_bar();

    for (int i = 0; i < 14; ++i) {
        int t1 = 2 * i + 1, t2 = 2 * i + 2, t3 = 2 * i + 3;
        // ph1: compute buf0 strip0 kh0 | stage buf1.Astrip1<-t1, buf1.Bnh0<-t1
        PHASE(0, 0, 0,
              { stageA(sA + 16384 + 8192, 1, t1); stageB(sB + 16384, 0, t1); }, {});
        // ph2: buf0 strip0 kh1 | stage buf1.Bnh1<-t1
        PHASE(0, 0, 1, { stageB(sB + 16384 + 8192, 1, t1); }, {});
        // ph3: buf0 strip1 kh0 | stage buf0.Astrip0<-t2
        PHASE(0, 1, 0, { stageA(sA + 0, 0, t2); }, {});
        // ph4: buf0 strip1 kh1 | wait: t1 resident (leave ph3's 2 loads in flight)
        PHASE(0, 1, 1, {}, { asm volatile("s_waitcnt vmcnt(2)" ::: "memory"); });
        // ph5: buf1 strip0 kh0 | stage buf0.Astrip1<-t2
        PHASE(16384, 0, 0, { stageA(sA + 8192, 1, t2); }, {});
        // ph6: buf1 strip0 kh1 | stage buf0.Bnh0<-t2
        PHASE(16384, 0, 1, { stageB(sB + 0, 0, t2); }, {});
        // ph7: buf1 strip1 kh0 | stage buf0.Bnh1<-t2
        PHASE(16384, 1, 0, { stageB(sB + 8192, 1, t2); }, {});
        // ph8: buf1 strip1 kh1 | stage buf1.Astrip0<-t3 ; wait: t2 resident
        PHASE(16384, 1, 1, { stageA(sA + 16384, 0, t3); },
              { asm volatile("s_waitcnt vmcnt(2)" ::: "memory"); });
    }
    asm volatile("s_waitcnt vmcnt(0)" ::: "memory");
    block_bar();
#undef PHASE
}

// GEMM1: feats = bf16( inp·wb^T + bias + coord terms )
__global__ __launch_bounds__(512) void k_gemm1(const bf16_t* __restrict__ inp, const bf16_t* __restrict__ wb,
                                               const float* __restrict__ cw, const float* __restrict__ cb,
                                               bf16_t* __restrict__ feats) {
    __shared__ __align__(16) bf16_t lds[65536];
    int wg = xcd_swz(blockIdx.x, NT * JT1);
    int n0 = (wg / JT1) * 256, j0 = (wg % JT1) * 256;
    f32x4 acc[8][4];
    gemm256(inp, wb, n0, j0, acc, lds);

    const int lane = threadIdx.x & 63, wid = threadIdx.x >> 6;
    const int wr = wid >> 2, wc = wid & 3, lr = lane & 15, lg = lane >> 4;
    float w1[4], w2[4], bb[4];
    int oc[4];
    #pragma unroll
    for (int fn = 0; fn < 4; ++fn) {
        int o = j0 + wc * 64 + fn * 16 + lr;
        oc[fn] = o;
        bb[fn] = cb[o];
        w1[fn] = cw[(size_t)o * CIN + DIMK];
        w2[fn] = cw[(size_t)o * CIN + DIMK + 1];
    }
    #pragma unroll
    for (int fm = 0; fm < 8; ++fm) {
        #pragma unroll
        for (int v = 0; v < 4; ++v) {
            int n = n0 + wr * 128 + fm * 16 + lg * 4 + v;
            int hw = n % HWv;
            int h = hw / WW, w = hw - h * WW;
            float xx = (2.f / 55.f) * w - 1.f;
            float yy = (2.f / 55.f) * h - 1.f;
            #pragma unroll
            for (int fn = 0; fn < 4; ++fn) {
                float phi = acc[fm][fn][v] + bb[fn] + xx * w1[fn] + yy * w2[fn];
                feats[(size_t)n * KP + oc[fn]] = (bf16_t)phi;
            }
        }
    }
}

// GEMM2 + fused per-row top3 of s = csq[m] - 2*dot  (partial per j-tile)
__global__ __launch_bounds__(512) void k_gemm2(const bf16_t* __restrict__ feats, const bf16_t* __restrict__ bt,
                                               const float* __restrict__ csq, float* __restrict__ partial) {
    __shared__ __align__(16) bf16_t lds[65536];
    int wg = xcd_swz(blockIdx.x, NT * JT2);
    int nt = wg / JT2, jt = wg % JT2;
    int n0 = nt * 256, j0 = jt * 256;
    f32x4 acc[8][4];
    gemm256(feats, bt, n0, j0, acc, lds);

    const int tid = threadIdx.x;
    const int lane = tid & 63, wid = tid >> 6;
    const int wr = wid >> 2, wc = wid & 3, lr = lane & 15, lg = lane >> 4;

    float csqv[4];
    bool mval[4];
    #pragma unroll
    for (int fn = 0; fn < 4; ++fn) {
        int m = j0 + wc * 64 + fn * 16 + lr;
        mval[fn] = (m < MM);
        csqv[fn] = mval[fn] ? csq[m] : 0.f;
    }

    float* lf  = (float*)lds;                 // [128][64][3]
    float* lf2 = lf + 128 * 64 * 3;           // [128][4][3]
    const int gidx = wc * 16 + lr;
    const float BIG = 3.0e38f;

    for (int pass = 0; pass < 2; ++pass) {
        if (wr == pass) {
            #pragma unroll
            for (int fm = 0; fm < 8; ++fm) {
                #pragma unroll
                for (int v = 0; v < 4; ++v) {
                    float a0 = mval[0] ? csqv[0] - 2.f * acc[fm][0][v] : BIG;
                    float a1 = mval[1] ? csqv[1] - 2.f * acc[fm][1][v] : BIG;
                    float a2 = mval[2] ? csqv[2] - 2.f * acc[fm][2][v] : BIG;
                    float a3 = mval[3] ? csqv[3] - 2.f * acc[fm][3][v] : BIG;
                    float t;
                    if (a0 > a1) { t = a0; a0 = a1; a1 = t; }
                    if (a2 > a3) { t = a2; a2 = a3; a3 = t; }
                    if (a0 > a2) { t = a0; a0 = a2; a2 = t; }
                    if (a1 > a3) { t = a1; a1 = a3; a3 = t; }
                    if (a1 > a2) { t = a1; a1 = a2; a2 = t; }
                    int rl = fm * 16 + lg * 4 + v;
                    int bix = (rl * 64 + gidx) * 3;
                    lf[bix] = a0; lf[bix + 1] = a1; lf[bix + 2] = a2;
                }
            }
        }
        __syncthreads();
        {
            int row = tid >> 2, seg = tid & 3;
            int base = (row * 64 + seg * 16) * 3;
            float d0 = lf[base], d1 = lf[base + 1], d2 = lf[base + 2];
            #pragma unroll
            for (int j2 = 1; j2 < 16; ++j2)
                merge3(d0, d1, d2, lf[base + j2 * 3], lf[base + j2 * 3 + 1], lf[base + j2 * 3 + 2]);
            int o2 = (row * 4 + seg) * 3;
            lf2[o2] = d0; lf2[o2 + 1] = d1; lf2[o2 + 2] = d2;
        }
        __syncthreads();
        if (tid < 128) {
            int base = tid * 12;
            float d0 = lf2[base], d1 = lf2[base + 1], d2 = lf2[base + 2];
            #pragma unroll
            for (int sg = 1; sg < 4; ++sg)
                merge3(d0, d1, d2, lf2[base + sg * 3], lf2[base + sg * 3 + 1], lf2[base + sg * 3 + 2]);
            size_t grow = (size_t)(n0 + pass * 128 + tid);
            float* pp = partial + grow * (JT2 * 3) + jt * 3;
            pp[0] = d0; pp[1] = d1; pp[2] = d2;
        }
        __syncthreads();
    }
}

__global__ __launch_bounds__(256) void k_fsq(const bf16_t* __restrict__ feats, float* __restrict__ fsq) {
    int n = blockIdx.x * 4 + (threadIdx.x >> 6);
    int lane = threadIdx.x & 63;
    const bf16_t* row = feats + (size_t)n * KP;
    float s = 0.f;
    #pragma unroll
    for (int t = 0; t < 28; ++t) { float v = (float)row[t * 64 + lane]; s += v * v; }
    #pragma unroll
    for (int off = 32; off; off >>= 1) s += __shfl_xor(s, off, 64);
    if (lane == 0) fsq[n] = s;
}

__global__ __launch_bounds__(256) void k_score(const float* __restrict__ partial, const float* __restrict__ fsq,
                                               float* __restrict__ out) {
    int row = blockIdx.x * 256 + threadIdx.x;
    if (row >= NROWS) return;
    const float* p = partial + (size_t)row * (JT2 * 3);
    float d0 = p[0], d1 = p[1], d2 = p[2];
    #pragma unroll
    for (int jt = 1; jt < JT2; ++jt)
        merge3(d0, d1, d2, p[jt * 3], p[jt * 3 + 1], p[jt * 3 + 2]);
    float fs = fsq[row];
    d0 = sqrtf(fmaxf(fs + d0, 0.f));
    d1 = sqrtf(fmaxf(fs + d1, 0.f));
    d2 = sqrtf(fmaxf(fs + d2, 0.f));
    float e1 = expf(d0 - d1), e2 = expf(d0 - d2);
    out[row] = d0 / (1.f + e1 + e2);
}

// ---------------- launch ----------------

extern "C" void kernel_launch(void* const* d_in, const int* in_sizes, int n_in,
                              void* d_out, int out_size, void* d_ws, size_t ws_size,
                              hipStream_t stream) {
    const float* f1   = (const float*)d_in[0];
    const float* f2   = (const float*)d_in[1];
    const float* f3   = (const float*)d_in[2];
    const float* cw   = (const float*)d_in[3];
    const float* cb   = (const float*)d_in[4];
    const float* bank = (const float*)d_in[5];
    float* out = (float*)d_out;
    char* ws = (char*)d_ws;

    size_t off = 0;
    auto alloc = [&](size_t bytes) { size_t o = off; off = (off + bytes + 255) & ~(size_t)255; return o; };
    bf16_t* wb      = (bf16_t*)(ws + alloc((size_t)COUT * KP * 2));
    bf16_t* bt      = (bf16_t*)(ws + alloc((size_t)MROWS * KP * 2));
    float*  fsq     = (float*)(ws + alloc((size_t)NROWS * 4));
    float*  csq     = (float*)(ws + alloc((size_t)MM * 4));
    float*  partial = (float*)(ws + alloc((size_t)NROWS * JT2 * 3 * 4));
    bf16_t* inp     = (bf16_t*)(ws + alloc((size_t)NROWS * KP * 2));
    bf16_t* feats   = (bf16_t*)(ws + alloc((size_t)NROWS * KP * 2));
    // p2/p3 alias the feats region (dead before gemm1 writes feats)
    float*  p2 = (float*)feats;
    float*  p3 = p2 + (size_t)8 * 512 * 28 * 28;

    k_convw<<<dim3((COUT * DIMK + 255) / 256), dim3(256), 0, stream>>>(cw, wb);
    k_bankT<<<dim3(MROWS / 64, DIMK / 64), dim3(256), 0, stream>>>(bank, bt);
    k_csq<<<dim3(MM), dim3(256), 0, stream>>>(bt, csq);
    k_pool1<<<dim3(HWv, 8), dim3(256), 0, stream>>>(f1, inp);
    k_pool_s<<<dim3((8 * 512 * 784 + 255) / 256), dim3(256), 0, stream>>>(f2, p2, 28, 8 * 512 * 784);
    k_pool_s<<<dim3((8 * 1024 * 196 + 255) / 256), dim3(256), 0, stream>>>(f3, p3, 14, 8 * 1024 * 196);
    k_resize<<<dim3(HWv, 8, 2), dim3(256), 0, stream>>>(p2, inp, 28, 512, 256, 0.5f, -0.25f);
    k_resize<<<dim3(HWv, 8, 4), dim3(256), 0, stream>>>(p3, inp, 14, 1024, 768, 0.25f, -0.375f);
    k_gemm1<<<dim3(NT * JT1), dim3(512), 0, stream>>>(inp, wb, cw, cb, feats);
    k_fsq<<<dim3(NROWS / 4), dim3(256), 0, stream>>>(feats, fsq);
    k_gemm2<<<dim3(NT * JT2), dim3(512), 0, stream>>>(feats, bt, csq, partial);
    k_score<<<dim3((NROWS + 255) / 256), dim3(256), 0, stream>>>(partial, fsq, out);
}

// Round 3
// 753.054 us; speedup vs baseline: 2.4183x; 1.4195x over previous
//
#include <hip/hip_runtime.h>
#include <hip/hip_bf16.h>
#include <math.h>

#define HH 56
#define WW 56
#define HWv 3136
#define NROWS 25088          // B*H*W
#define DIMK 1792
#define KP   1920            // padded K stride (30 tiles of 64; tiles 28,29 staged-only)
#define CIN 1794
#define COUT 1792
#define MM 3136
#define MROWS 3328           // 13 * 256
#define JT2 13
#define JT1 7
#define NT 98

typedef __bf16 bf16_t;
typedef __bf16 bf16x8 __attribute__((ext_vector_type(8)));
typedef float f32x4 __attribute__((ext_vector_type(4)));

__device__ __forceinline__ void merge3(float& d0, float& d1, float& d2,
                                       float e0, float e1, float e2) {
    bool t0 = d0 <= e0;
    float c0 = t0 ? d0 : e0;
    float x0 = t0 ? d1 : d0, x1 = t0 ? d2 : d1;
    float y0 = t0 ? e0 : e1, y1 = t0 ? e1 : e2;
    bool t1 = x0 <= y0;
    float c1 = t1 ? x0 : y0;
    float c2 = t1 ? fminf(x1, y0) : fminf(x0, y1);
    d0 = c0; d1 = c1; d2 = c2;
}

__device__ __forceinline__ int xcd_swz(int wg, int nwg) {
    int x = wg & 7, idx = wg >> 3;
    int q = nwg >> 3, r = nwg & 7;
    return (x < r ? x * (q + 1) : r * (q + 1) + (x - r) * q) + idx;
}

__device__ __forceinline__ void block_bar() {
    asm volatile("" ::: "memory");
    __builtin_amdgcn_s_barrier();
    asm volatile("" ::: "memory");
}

// ---------------- prep kernels ----------------

__global__ __launch_bounds__(256) void k_convw(const float* __restrict__ cw, bf16_t* __restrict__ wb) {
    int idx = blockIdx.x * 256 + threadIdx.x;
    if (idx >= COUT * DIMK) return;
    int o = idx / DIMK, c = idx - o * DIMK;
    wb[(size_t)o * KP + c] = (bf16_t)cw[(size_t)o * CIN + c];
}

// tiled transpose bank[C,M] -> bt[MROWS,KP] (bf16), zero pad rows
__global__ __launch_bounds__(256) void k_bankT(const float* __restrict__ bank, bf16_t* __restrict__ bt) {
    __shared__ float tile[64][65];
    int mt = blockIdx.x * 64;
    int ct = blockIdx.y * 64;
    int l = threadIdx.x & 63;
    int q = threadIdx.x >> 6;
    if (mt < MM) {
        #pragma unroll
        for (int r = 0; r < 16; ++r) {
            int cl = q * 16 + r;
            tile[cl][l] = bank[(size_t)(ct + cl) * MM + mt + l];
        }
        __syncthreads();
        #pragma unroll
        for (int r = 0; r < 16; ++r) {
            int ml = q * 16 + r;
            bt[(size_t)(mt + ml) * KP + ct + l] = (bf16_t)tile[l][ml];
        }
    } else {
        #pragma unroll
        for (int r = 0; r < 16; ++r) {
            int ml = q * 16 + r;
            bt[(size_t)(mt + ml) * KP + ct + l] = (bf16_t)0.f;
        }
    }
}

// vectorized sum-of-squares over a [*, KP] bf16 matrix row (first 1792 cols)
__global__ __launch_bounds__(256) void k_rowsq(const bf16_t* __restrict__ rows, float* __restrict__ sq) {
    int n = blockIdx.x * 4 + (threadIdx.x >> 6);
    int lane = threadIdx.x & 63;
    const bf16x8* row = (const bf16x8*)(rows + (size_t)n * KP);
    float s = 0.f;
    #pragma unroll
    for (int t = 0; t < 4; ++t) {
        int idx = t * 64 + lane;
        if (idx < 224) {
            bf16x8 v = row[idx];
            #pragma unroll
            for (int j = 0; j < 8; ++j) { float f = (float)v[j]; s += f * f; }
        }
    }
    #pragma unroll
    for (int off = 32; off; off >>= 1) s += __shfl_xor(s, off, 64);
    if (lane == 0) sq[n] = s;
}

__global__ __launch_bounds__(256) void k_pool_s(const float* __restrict__ in, float* __restrict__ out,
                                                int S, int total) {
    int idx = blockIdx.x * 256 + threadIdx.x;
    if (idx >= total) return;
    int x = idx % S; int y = (idx / S) % S; int bc = idx / (S * S);
    const float* base = in + (size_t)bc * S * S;
    float s = 0.f;
    for (int dy = -1; dy <= 1; ++dy) {
        int yy = y + dy; if ((unsigned)yy >= (unsigned)S) continue;
        for (int dx = -1; dx <= 1; ++dx) {
            int xx = x + dx; if ((unsigned)xx >= (unsigned)S) continue;
            s += base[yy * S + xx];
        }
    }
    out[idx] = s * (1.f / 9.f);
}

// planar bilinear resize S*S -> 56x56, bf16 out (coalesced both sides)
__global__ __launch_bounds__(256) void k_resize_p(const float* __restrict__ src, bf16_t* __restrict__ dst,
                                                  int S, int total, float scale, float shift) {
    int idx = blockIdx.x * 256 + threadIdx.x;
    if (idx >= total) return;
    int w = idx % WW; int h = (idx / WW) % HH; int bc = idx / HWv;
    float sy = scale * h + shift;
    float sx = scale * w + shift;
    float y0f = floorf(sy), x0f = floorf(sx);
    int y0 = (int)y0f, x0 = (int)x0f;
    float fy = sy - y0f, fx = sx - x0f;
    int iy0 = y0 < 0 ? 0 : (y0 > S - 1 ? S - 1 : y0);
    int iy1 = (y0 + 1) < 0 ? 0 : ((y0 + 1) > S - 1 ? S - 1 : y0 + 1);
    int ix0 = x0 < 0 ? 0 : (x0 > S - 1 ? S - 1 : x0);
    int ix1 = (x0 + 1) < 0 ? 0 : ((x0 + 1) > S - 1 ? S - 1 : x0 + 1);
    const float* base = src + (size_t)bc * S * S;
    float v00 = base[iy0 * S + ix0], v01 = base[iy0 * S + ix1];
    float v10 = base[iy1 * S + ix0], v11 = base[iy1 * S + ix1];
    float v = (1.f - fy) * ((1.f - fx) * v00 + fx * v01) + fy * ((1.f - fx) * v10 + fx * v11);
    dst[idx] = (bf16_t)v;
}

// LDS-tiled transpose-concat: planar src[b][Csrc][3136] -> inp[(b,hw)][coff+c]
template <typename T>
__global__ __launch_bounds__(256) void k_transp(const T* __restrict__ src, bf16_t* __restrict__ inp,
                                                int Csrc, int coff) {
    __shared__ float tile[64][65];
    int hw0 = blockIdx.x * 64;
    int c0 = blockIdx.y * 64;
    int b = blockIdx.z;
    int l = threadIdx.x & 63;
    int q = threadIdx.x >> 6;
    #pragma unroll
    for (int r = 0; r < 16; ++r) {
        int c = q * 16 + r;
        tile[c][l] = (float)src[(size_t)(b * Csrc + c0 + c) * HWv + hw0 + l];
    }
    __syncthreads();
    #pragma unroll
    for (int r = 0; r < 16; ++r) {
        int ml = q * 16 + r;
        inp[(size_t)(b * HWv + hw0 + ml) * KP + coff + c0 + l] = (bf16_t)tile[l][ml];
    }
}

// ---------------- 256x256 8-phase GEMM core (quadrant phases, unit recycling) ----
// LDS: sA = lds[0..32768), sB = lds[32768..65536) (bf16)
// unit = [256 rows][32 k] = 8192 elems; per operand: [2 buf][2 kh] units.
// swizzle: 16B-granule gc within a row stores source granule gc ^ ((row>>1)&3).

__device__ __forceinline__ void gemm256(const bf16_t* __restrict__ A, const bf16_t* __restrict__ Bm,
                                        int n0, int j0, f32x4 (&acc)[8][4], bf16_t* lds) {
    const int tid = threadIdx.x;
    const int lane = tid & 63;
    const int wid = tid >> 6;
    const int wr = wid >> 2;          // 0..1 (M half)
    const int wc = wid & 3;           // 0..3 (N quarter)
    const int lr = lane & 15;
    const int lg = lane >> 4;

    bf16_t* sA = lds;
    bf16_t* sB = lds + 32768;

    #pragma unroll
    for (int i = 0; i < 8; ++i)
        #pragma unroll
        for (int j = 0; j < 4; ++j) acc[i][j] = (f32x4){0.f, 0.f, 0.f, 0.f};

    // stage one unit (256 rows x 32 k) from src rows row0.., k col kc
    auto stage = [&](bf16_t* dst, const bf16_t* src, int row0, int kc) {
        #pragma unroll
        for (int r = 0; r < 2; ++r) {
            int g = r * 512 + tid;          // granule 0..1023
            int rp = g >> 2;
            int gc = g & 3;
            int gcs = gc ^ ((rp >> 1) & 3);
            __builtin_amdgcn_global_load_lds(
                (__attribute__((address_space(1))) void*)(src + (size_t)(row0 + rp) * KP + kc + gcs * 8),
                (__attribute__((address_space(3))) void*)(dst + g * 8), 16, 0, 0);
        }
    };

#define PHASE(BUF, MH, KH, STAGE_CODE, TAIL_CODE)                                          \
    {                                                                                      \
        bf16_t* au = sA + (BUF) * 16384 + (KH) * 8192;                                     \
        bf16_t* bu = sB + (BUF) * 16384 + (KH) * 8192;                                     \
        bf16x8 aF[4], bF[4];                                                               \
        _Pragma("unroll")                                                                  \
        for (int q = 0; q < 4; ++q) {                                                      \
            int ra = wr * 128 + (MH) * 64 + q * 16 + lr;                                   \
            aF[q] = *(const bf16x8*)(au + ra * 32 + ((lg ^ ((ra >> 1) & 3)) * 8));         \
            int rb = wc * 64 + q * 16 + lr;                                                \
            bF[q] = *(const bf16x8*)(bu + rb * 32 + ((lg ^ ((rb >> 1) & 3)) * 8));         \
        }                                                                                  \
        STAGE_CODE;                                                                        \
        block_bar();                                                                       \
        __builtin_amdgcn_s_setprio(1);                                                     \
        _Pragma("unroll")                                                                  \
        for (int q = 0; q < 4; ++q)                                                        \
            _Pragma("unroll")                                                              \
            for (int fn = 0; fn < 4; ++fn)                                                 \
                acc[(MH) * 4 + q][fn] = __builtin_amdgcn_mfma_f32_16x16x32_bf16(           \
                    aF[q], bF[fn], acc[(MH) * 4 + q][fn], 0, 0, 0);                        \
        __builtin_amdgcn_s_setprio(0);                                                     \
        TAIL_CODE;                                                                         \
        block_bar();                                                                       \
    }

    // prologue: buf0 all 4 units <- t0; buf1 k0 units <- t1
    stage(sA + 0,             A,  n0, 0);        // buf0.A_k0
    stage(sB + 0,             Bm, j0, 0);        // buf0.B_k0
    stage(sA + 8192,          A,  n0, 32);       // buf0.A_k1
    stage(sB + 8192,          Bm, j0, 32);       // buf0.B_k1
    stage(sA + 16384,         A,  n0, 64);       // buf1.A_k0 <- t1
    stage(sB + 16384,         Bm, j0, 64);       // buf1.B_k0 <- t1
    asm volatile("s_waitcnt vmcnt(4)" ::: "memory");   // buf0 fully resident
    block_bar();

    for (int i = 0; i < 14; ++i) {
        int k1 = (2 * i + 1) * 64, k2 = (2 * i + 2) * 64, k3 = (2 * i + 3) * 64;
        // buf0 = tile 2i, buf1 = tile 2i+1
        PHASE(0, 0, 0, { stage(sA + 16384 + 8192, A,  n0, k1 + 32); }, {});   // buf1.A_k1<-t1
        PHASE(0, 1, 0, { stage(sB + 16384 + 8192, Bm, j0, k1 + 32); }, {});   // buf1.B_k1<-t1
        PHASE(0, 0, 1, { stage(sA + 0,            A,  n0, k2); }, {});        // buf0.A_k0<-t2
        PHASE(0, 1, 1, { stage(sB + 0,            Bm, j0, k2); },
              { asm volatile("s_waitcnt vmcnt(4)" ::: "memory"); });          // buf1 t1 ready
        PHASE(1, 0, 0, { stage(sA + 8192,         A,  n0, k2 + 32); }, {});   // buf0.A_k1<-t2
        PHASE(1, 1, 0, { stage(sB + 8192,         Bm, j0, k2 + 32); }, {});   // buf0.B_k1<-t2
        PHASE(1, 0, 1, { stage(sA + 16384,        A,  n0, k3); }, {});        // buf1.A_k0<-t3
        PHASE(1, 1, 1, { stage(sB + 16384,        Bm, j0, k3); },
              { asm volatile("s_waitcnt vmcnt(4)" ::: "memory"); });          // buf0 t2 ready
    }
    asm volatile("s_waitcnt vmcnt(0)" ::: "memory");
    block_bar();
#undef PHASE
}

// GEMM1: feats = bf16( inp·wb^T + bias + coord terms )
__global__ __launch_bounds__(512) void k_gemm1(const bf16_t* __restrict__ inp, const bf16_t* __restrict__ wb,
                                               const float* __restrict__ cw, const float* __restrict__ cb,
                                               bf16_t* __restrict__ feats) {
    __shared__ __align__(16) bf16_t lds[65536];
    int wg = xcd_swz(blockIdx.x, NT * JT1);
    int n0 = (wg / JT1) * 256, j0 = (wg % JT1) * 256;
    f32x4 acc[8][4];
    gemm256(inp, wb, n0, j0, acc, lds);

    const int lane = threadIdx.x & 63, wid = threadIdx.x >> 6;
    const int wr = wid >> 2, wc = wid & 3, lr = lane & 15, lg = lane >> 4;
    float w1[4], w2[4], bb[4];
    int oc[4];
    #pragma unroll
    for (int fn = 0; fn < 4; ++fn) {
        int o = j0 + wc * 64 + fn * 16 + lr;
        oc[fn] = o;
        bb[fn] = cb[o];
        w1[fn] = cw[(size_t)o * CIN + DIMK];
        w2[fn] = cw[(size_t)o * CIN + DIMK + 1];
    }
    #pragma unroll
    for (int mh = 0; mh < 2; ++mh) {
        #pragma unroll
        for (int q = 0; q < 4; ++q) {
            #pragma unroll
            for (int v = 0; v < 4; ++v) {
                int n = n0 + wr * 128 + mh * 64 + q * 16 + lg * 4 + v;
                int hw = n % HWv;
                int h = hw / WW, w = hw - h * WW;
                float xx = (2.f / 55.f) * w - 1.f;
                float yy = (2.f / 55.f) * h - 1.f;
                #pragma unroll
                for (int fn = 0; fn < 4; ++fn) {
                    float phi = acc[mh * 4 + q][fn][v] + bb[fn] + xx * w1[fn] + yy * w2[fn];
                    feats[(size_t)n * KP + oc[fn]] = (bf16_t)phi;
                }
            }
        }
    }
}

// GEMM2 + fused per-row top3 of s = csq[m] - 2*dot  (partial per j-tile)
__global__ __launch_bounds__(512) void k_gemm2(const bf16_t* __restrict__ feats, const bf16_t* __restrict__ bt,
                                               const float* __restrict__ csq, float* __restrict__ partial) {
    __shared__ __align__(16) bf16_t lds[65536];
    int wg = xcd_swz(blockIdx.x, NT * JT2);
    int nt = wg / JT2, jt = wg % JT2;
    int n0 = nt * 256, j0 = jt * 256;
    f32x4 acc[8][4];
    gemm256(feats, bt, n0, j0, acc, lds);

    const int tid = threadIdx.x;
    const int lane = tid & 63, wid = tid >> 6;
    const int wr = wid >> 2, wc = wid & 3, lr = lane & 15, lg = lane >> 4;

    float csqv[4];
    bool mval[4];
    #pragma unroll
    for (int fn = 0; fn < 4; ++fn) {
        int m = j0 + wc * 64 + fn * 16 + lr;
        mval[fn] = (m < MM);
        csqv[fn] = mval[fn] ? csq[m] : 0.f;
    }

    float* lf  = (float*)lds;                 // [128][64][3]
    float* lf2 = lf + 128 * 64 * 3;           // [128][4][3]
    const int gidx = wc * 16 + lr;
    const float BIG = 3.0e38f;

    for (int pass = 0; pass < 2; ++pass) {
        if (wr == pass) {
            #pragma unroll
            for (int mh = 0; mh < 2; ++mh) {
                #pragma unroll
                for (int q = 0; q < 4; ++q) {
                    #pragma unroll
                    for (int v = 0; v < 4; ++v) {
                        float a0 = mval[0] ? csqv[0] - 2.f * acc[mh * 4 + q][0][v] : BIG;
                        float a1 = mval[1] ? csqv[1] - 2.f * acc[mh * 4 + q][1][v] : BIG;
                        float a2 = mval[2] ? csqv[2] - 2.f * acc[mh * 4 + q][2][v] : BIG;
                        float a3 = mval[3] ? csqv[3] - 2.f * acc[mh * 4 + q][3][v] : BIG;
                        float t;
                        if (a0 > a1) { t = a0; a0 = a1; a1 = t; }
                        if (a2 > a3) { t = a2; a2 = a3; a3 = t; }
                        if (a0 > a2) { t = a0; a0 = a2; a2 = t; }
                        if (a1 > a3) { t = a1; a1 = a3; a3 = t; }
                        if (a1 > a2) { t = a1; a1 = a2; a2 = t; }
                        int rl = mh * 64 + q * 16 + lg * 4 + v;
                        int bix = (rl * 64 + gidx) * 3;
                        lf[bix] = a0; lf[bix + 1] = a1; lf[bix + 2] = a2;
                    }
                }
            }
        }
        __syncthreads();
        {
            int row = tid >> 2, seg = tid & 3;
            int base = (row * 64 + seg * 16) * 3;
            float d0 = lf[base], d1 = lf[base + 1], d2 = lf[base + 2];
            #pragma unroll
            for (int j2 = 1; j2 < 16; ++j2)
                merge3(d0, d1, d2, lf[base + j2 * 3], lf[base + j2 * 3 + 1], lf[base + j2 * 3 + 2]);
            int o2 = (row * 4 + seg) * 3;
            lf2[o2] = d0; lf2[o2 + 1] = d1; lf2[o2 + 2] = d2;
        }
        __syncthreads();
        if (tid < 128) {
            int base = tid * 12;
            float d0 = lf2[base], d1 = lf2[base + 1], d2 = lf2[base + 2];
            #pragma unroll
            for (int sg = 1; sg < 4; ++sg)
                merge3(d0, d1, d2, lf2[base + sg * 3], lf2[base + sg * 3 + 1], lf2[base + sg * 3 + 2]);
            size_t grow = (size_t)(n0 + pass * 128 + tid);
            float* pp = partial + grow * (JT2 * 3) + jt * 3;
            pp[0] = d0; pp[1] = d1; pp[2] = d2;
        }
        __syncthreads();
    }
}

__global__ __launch_bounds__(256) void k_score(const float* __restrict__ partial, const float* __restrict__ fsq,
                                               float* __restrict__ out) {
    int row = blockIdx.x * 256 + threadIdx.x;
    if (row >= NROWS) return;
    const float* p = partial + (size_t)row * (JT2 * 3);
    float d0 = p[0], d1 = p[1], d2 = p[2];
    #pragma unroll
    for (int jt = 1; jt < JT2; ++jt)
        merge3(d0, d1, d2, p[jt * 3], p[jt * 3 + 1], p[jt * 3 + 2]);
    float fs = fsq[row];
    d0 = sqrtf(fmaxf(fs + d0, 0.f));
    d1 = sqrtf(fmaxf(fs + d1, 0.f));
    d2 = sqrtf(fmaxf(fs + d2, 0.f));
    float e1 = expf(d0 - d1), e2 = expf(d0 - d2);
    out[row] = d0 / (1.f + e1 + e2);
}

// ---------------- launch ----------------

extern "C" void kernel_launch(void* const* d_in, const int* in_sizes, int n_in,
                              void* d_out, int out_size, void* d_ws, size_t ws_size,
                              hipStream_t stream) {
    const float* f1   = (const float*)d_in[0];
    const float* f2   = (const float*)d_in[1];
    const float* f3   = (const float*)d_in[2];
    const float* cw   = (const float*)d_in[3];
    const float* cb   = (const float*)d_in[4];
    const float* bank = (const float*)d_in[5];
    float* out = (float*)d_out;
    char* ws = (char*)d_ws;

    size_t off = 0;
    auto alloc = [&](size_t bytes) { size_t o = off; off = (off + bytes + 255) & ~(size_t)255; return o; };
    bf16_t* wb      = (bf16_t*)(ws + alloc((size_t)COUT * KP * 2));
    bf16_t* bt      = (bf16_t*)(ws + alloc((size_t)MROWS * KP * 2));
    float*  fsq     = (float*)(ws + alloc((size_t)NROWS * 4));
    float*  csq     = (float*)(ws + alloc((size_t)MM * 4));
    float*  partial = (float*)(ws + alloc((size_t)NROWS * JT2 * 3 * 4));
    bf16_t* inp     = (bf16_t*)(ws + alloc((size_t)NROWS * KP * 2));
    bf16_t* feats   = (bf16_t*)(ws + alloc((size_t)NROWS * KP * 2));

    // prep scratch aliased inside (currently dead) feats region:
    //   phase A: [p1 f32 25.7MB][p2s f32 12.9MB][r2b bf16 25.7MB]
    //   phase B (after p1/r2b consumed): [p3s f32 6.4MB][r3b bf16 51.4MB]
    char* fb = (char*)feats;
    float*  p1  = (float*)fb;
    float*  p2s = (float*)(fb + 25690112);
    bf16_t* r2b = (bf16_t*)(fb + 25690112 + 12845056);
    float*  p3s = (float*)fb;
    bf16_t* r3b = (bf16_t*)(fb + 6422528);

    k_convw<<<dim3((COUT * DIMK + 255) / 256), dim3(256), 0, stream>>>(cw, wb);
    k_bankT<<<dim3(MROWS / 64, DIMK / 64), dim3(256), 0, stream>>>(bank, bt);
    k_rowsq<<<dim3(MM / 4), dim3(256), 0, stream>>>(bt, csq);

    // f1: planar pool -> transpose
    k_pool_s<<<dim3((8 * 256 * HWv + 255) / 256), dim3(256), 0, stream>>>(f1, p1, 56, 8 * 256 * HWv);
    // f2: planar pool -> planar resize (bf16) -> transpose
    k_pool_s<<<dim3((8 * 512 * 784 + 255) / 256), dim3(256), 0, stream>>>(f2, p2s, 28, 8 * 512 * 784);
    k_resize_p<<<dim3((8 * 512 * HWv + 255) / 256), dim3(256), 0, stream>>>(p2s, r2b, 28, 8 * 512 * HWv, 0.5f, -0.25f);
    k_transp<float><<<dim3(HWv / 64, 256 / 64, 8), dim3(256), 0, stream>>>(p1, inp, 256, 0);
    k_transp<bf16_t><<<dim3(HWv / 64, 512 / 64, 8), dim3(256), 0, stream>>>(r2b, inp, 512, 256);
    // f3 (p1 now dead): planar pool -> planar resize -> transpose
    k_pool_s<<<dim3((8 * 1024 * 196 + 255) / 256), dim3(256), 0, stream>>>(f3, p3s, 14, 8 * 1024 * 196);
    k_resize_p<<<dim3((8 * 1024 * HWv + 255) / 256), dim3(256), 0, stream>>>(p3s, r3b, 14, 8 * 1024 * HWv, 0.25f, -0.375f);
    k_transp<bf16_t><<<dim3(HWv / 64, 1024 / 64, 8), dim3(256), 0, stream>>>(r3b, inp, 1024, 768);

    k_gemm1<<<dim3(NT * JT1), dim3(512), 0, stream>>>(inp, wb, cw, cb, feats);
    k_rowsq<<<dim3(NROWS / 4), dim3(256), 0, stream>>>(feats, fsq);
    k_gemm2<<<dim3(NT * JT2), dim3(512), 0, stream>>>(feats, bt, csq, partial);
    k_score<<<dim3((NROWS + 255) / 256), dim3(256), 0, stream>>>(partial, fsq, out);
}